// Round 8
// baseline (153.861 us; speedup 1.0000x reference)
//
#include <hip/hip_runtime.h>

#define B_ 4
#define C_ 64
#define H_ 96
#define W_ 96
#define KS_ 7
#define NPIX (H_ * W_)   // 9216
#define LDSTR 108        // attn LDS row stride (floats)

typedef __attribute__((ext_vector_type(8))) short short8;
typedef __attribute__((ext_vector_type(4))) float f32x4;

static __device__ inline ushort f2bf(float f) {
    union { float f; unsigned u; } v; v.f = f;
    unsigned r = (v.u + 0x7fff + ((v.u >> 16) & 1)) >> 16;   // RNE
    return (ushort)r;
}

// ws layout: qkv float[B][192][9216]  (rows 0-63 q, 64-127 k, 128-191 v)

// ---- MFMA conv: 32-pix x 192-oc tile per block; W,X,bias staged in LDS ----
__global__ __launch_bounds__(256) void mfma_conv_kernel(
    const float* __restrict__ in,          // [B][64][9216]
    const float* __restrict__ qw, const float* __restrict__ qb,
    const float* __restrict__ kw, const float* __restrict__ kb,
    const float* __restrict__ vw, const float* __restrict__ vb,
    float* __restrict__ qkv)               // [B][192][9216]
{
    const int b    = blockIdx.y;
    const int pix0 = blockIdx.x * 32;
    const int t    = threadIdx.x;
    const int lane = t & 63;
    const int wv   = t >> 6;

    __shared__ ushort wlds[192 * 64];   // 24 KB, byte ^= (row&7)<<4
    __shared__ ushort xs[32 * 64];      // 4 KB,  byte ^= (pix&7)<<4
    __shared__ float  bias_s[192];

    // stage W -> bf16 LDS (swizzled)
    #pragma unroll
    for (int g = 0; g < 12; ++g) {
        const int qq  = t + 256 * g;        // 0..3071 ushort4-chunks
        const int row = qq >> 4;
        const int c4  = (qq & 15) * 4;
        const float* src = (row < 64) ? qw + row * 64
                         : (row < 128) ? kw + (row - 64) * 64
                                       : vw + (row - 128) * 64;
        float4 f = *reinterpret_cast<const float4*>(src + c4);
        ushort4 u = make_ushort4(f2bf(f.x), f2bf(f.y), f2bf(f.z), f2bf(f.w));
        unsigned byte = (unsigned)(row * 128 + c4 * 2) ^ (unsigned)((row & 7) << 4);
        *reinterpret_cast<ushort4*>(reinterpret_cast<char*>(wlds) + byte) = u;
    }
    if (t < 192) {
        const int tensor = t >> 6;
        bias_s[t] = (tensor == 0 ? qb : tensor == 1 ? kb : vb)[t & 63];
    }
    // stage X tile (32 pix x 64 ch) -> bf16 LDS transposed (swizzled)
    {
        const int pix = t & 31, cg = t >> 5;
        const float* xp = in + (size_t)b * C_ * NPIX + pix0 + pix;
        #pragma unroll
        for (int g = 0; g < 2; ++g) {
            const int ch = (cg + 8 * g) * 4;
            float x0 = xp[(size_t)(ch    ) * NPIX];
            float x1 = xp[(size_t)(ch + 1) * NPIX];
            float x2 = xp[(size_t)(ch + 2) * NPIX];
            float x3 = xp[(size_t)(ch + 3) * NPIX];
            ushort4 u = make_ushort4(f2bf(x0), f2bf(x1), f2bf(x2), f2bf(x3));
            unsigned byte = (unsigned)(pix * 128 + ch * 2) ^ (unsigned)((pix & 7) << 4);
            *reinterpret_cast<ushort4*>(reinterpret_cast<char*>(xs) + byte) = u;
        }
    }
    __syncthreads();

    short8 afr[3][2];
    #pragma unroll
    for (int i = 0; i < 3; ++i) {
        const int row = (3 * wv + i) * 16 + (lane & 15);
        #pragma unroll
        for (int ka = 0; ka < 2; ++ka) {
            const int kk = ka * 32 + (lane >> 4) * 8;
            unsigned byte = (unsigned)(row * 128 + kk * 2) ^ (unsigned)((row & 7) << 4);
            afr[i][ka] = *reinterpret_cast<const short8*>(
                reinterpret_cast<const char*>(wlds) + byte);
        }
    }
    short8 bfr[2][2];
    #pragma unroll
    for (int nt = 0; nt < 2; ++nt) {
        const int pl = nt * 16 + (lane & 15);
        #pragma unroll
        for (int ka = 0; ka < 2; ++ka) {
            const int kk = ka * 32 + (lane >> 4) * 8;
            unsigned byte = (unsigned)(pl * 128 + kk * 2) ^ (unsigned)((pl & 7) << 4);
            bfr[nt][ka] = *reinterpret_cast<const short8*>(
                reinterpret_cast<const char*>(xs) + byte);
        }
    }
    f32x4 acc[3][2];
    #pragma unroll
    for (int i = 0; i < 3; ++i) {
        f32x4 bi;
        #pragma unroll
        for (int r = 0; r < 4; ++r)
            bi[r] = bias_s[(3 * wv + i) * 16 + (lane >> 4) * 4 + r];
        #pragma unroll
        for (int nt = 0; nt < 2; ++nt) acc[i][nt] = bi;
    }
    #pragma unroll
    for (int i = 0; i < 3; ++i) {
        #pragma unroll
        for (int nt = 0; nt < 2; ++nt) {
            acc[i][nt] = __builtin_amdgcn_mfma_f32_16x16x32_bf16(
                afr[i][0], bfr[nt][0], acc[i][nt], 0, 0, 0);
            acc[i][nt] = __builtin_amdgcn_mfma_f32_16x16x32_bf16(
                afr[i][1], bfr[nt][1], acc[i][nt], 0, 0, 0);
        }
    }
    #pragma unroll
    for (int i = 0; i < 3; ++i) {
        #pragma unroll
        for (int r = 0; r < 4; ++r) {
            const int row = (3 * wv + i) * 16 + (lane >> 4) * 4 + r;
            float* op = qkv + ((size_t)b * 192 + row) * NPIX + pix0 + (lane & 15);
            #pragma unroll
            for (int nt = 0; nt < 2; ++nt)
                op[nt * 16] = acc[i][nt][r];
        }
    }
}

// ---- attention: block = (b,c,32-row tile); borders = bias at staging ----
__global__ __launch_bounds__(384) void attn_kernel(
    const float* __restrict__ qkv,
    const float* __restrict__ kb, const float* __restrict__ vb,
    const float* __restrict__ relh, const float* __restrict__ relw,
    float* __restrict__ out)
{
    const int bx   = blockIdx.x;
    const int tile = bx % 3;
    const int c    = (bx / 3) % C_;
    const int b    = bx / (3 * C_);
    const int ho0  = tile * 32;
    const int t    = threadIdx.x;

    __shared__ float ks[38 * LDSTR];
    __shared__ float vs[38 * LDSTR];
    __shared__ float rel_s[49];

    if (t < 49) {
        const int i = t / KS_, j = t % KS_;
        float s = 0.f;
        #pragma unroll
        for (int cc = 0; cc < C_ / 2; ++cc)
            s += relh[cc * KS_ + i] + relw[cc * KS_ + j];
        rel_s[t] = s;
    }
    {
        const float kbias = kb[c];
        const float vbias = vb[c];
        const float* kg = qkv + ((size_t)b * 192 +  64 + c) * NPIX;
        const float* vg = qkv + ((size_t)b * 192 + 128 + c) * NPIX;
        for (int idx = t; idx < 38 * 104; idx += 384) {
            const int rl = idx / 104, cl = idx - rl * 104;
            const int gr = ho0 + rl - 3, gc = cl - 3;
            const bool inb = (gr >= 0 && gr < H_ && gc >= 0 && gc < W_);
            const int gi = gr * W_ + gc;
            ks[rl * LDSTR + cl] = inb ? kg[gi] : kbias;
            vs[rl * LDSTR + cl] = inb ? vg[gi] : vbias;
        }
    }
    __syncthreads();

    const int r0   = t / 12;
    const int rest = t % 12;
    const int w0   = (rest >> 1) * 16;
    const int half = rest & 1;
    const int ho   = ho0 + r0;

    const float* qp = qkv + ((size_t)b * 192 + c) * NPIX + ho * W_ + w0;
    float qs[16];
    #pragma unroll
    for (int tt = 0; tt < 16; tt += 4) {
        float4 f = *reinterpret_cast<const float4*>(qp + tt);
        qs[tt] = f.x; qs[tt + 1] = f.y; qs[tt + 2] = f.z; qs[tt + 3] = f.w;
    }
    float qsum = 0.f;
    #pragma unroll
    for (int tt = 0; tt < 16; ++tt) qsum += qs[tt];

    float logit[49];
    #pragma unroll
    for (int i = 0; i < KS_; ++i) {
        float kr[22];
        const float* kp = &ks[(r0 + i) * LDSTR + w0];
        #pragma unroll
        for (int tt = 0; tt < 20; tt += 4) {
            float4 f = *reinterpret_cast<const float4*>(kp + tt);
            kr[tt] = f.x; kr[tt + 1] = f.y; kr[tt + 2] = f.z; kr[tt + 3] = f.w;
        }
        float2 f2 = *reinterpret_cast<const float2*>(kp + 20);
        kr[20] = f2.x; kr[21] = f2.y;
        #pragma unroll
        for (int j = 0; j < KS_; ++j) {
            float s0 = 0.f, s1 = 0.f, s2 = 0.f, s3 = 0.f;
            #pragma unroll
            for (int tt = 0; tt < 16; tt += 4) {
                s0 = fmaf(qs[tt],     kr[tt + j],     s0);
                s1 = fmaf(qs[tt + 1], kr[tt + 1 + j], s1);
                s2 = fmaf(qs[tt + 2], kr[tt + 2 + j], s2);
                s3 = fmaf(qs[tt + 3], kr[tt + 3 + j], s3);
            }
            logit[i * KS_ + j] = (s0 + s1) + (s2 + s3) + qsum * rel_s[i * KS_ + j];
        }
    }

    // softmax over 49 (4-way trees)
    float m0 = logit[0], m1 = logit[1], m2 = logit[2], m3 = logit[3];
    #pragma unroll
    for (int kk = 4; kk < 48; kk += 4) {
        m0 = fmaxf(m0, logit[kk]);
        m1 = fmaxf(m1, logit[kk + 1]);
        m2 = fmaxf(m2, logit[kk + 2]);
        m3 = fmaxf(m3, logit[kk + 3]);
    }
    float m = fmaxf(fmaxf(m0, m1), fmaxf(m2, m3));
    m = fmaxf(m, logit[48]);

    float e0 = 0.f, e1 = 0.f, e2 = 0.f, e3 = 0.f;
    #pragma unroll
    for (int kk = 0; kk < 48; kk += 4) {
        float a0 = __expf(logit[kk]     - m);
        float a1 = __expf(logit[kk + 1] - m);
        float a2 = __expf(logit[kk + 2] - m);
        float a3 = __expf(logit[kk + 3] - m);
        logit[kk] = a0; logit[kk + 1] = a1; logit[kk + 2] = a2; logit[kk + 3] = a3;
        e0 += a0; e1 += a1; e2 += a2; e3 += a3;
    }
    float a48 = __expf(logit[48] - m);
    logit[48] = a48;
    const float inv = 1.f / ((e0 + e1) + (e2 + e3) + a48);

    // PV for d = half*8 .. half*8+7
    float o8[8];
    #pragma unroll
    for (int d = 0; d < 8; ++d) o8[d] = 0.f;

    #pragma unroll
    for (int i = 0; i < KS_; ++i) {
        float vr[14];
        const float* vp = &vs[(r0 + i) * LDSTR + w0 + half * 8];
        #pragma unroll
        for (int tt = 0; tt < 12; tt += 4) {
            float4 f = *reinterpret_cast<const float4*>(vp + tt);
            vr[tt] = f.x; vr[tt + 1] = f.y; vr[tt + 2] = f.z; vr[tt + 3] = f.w;
        }
        float2 f2 = *reinterpret_cast<const float2*>(vp + 12);
        vr[12] = f2.x; vr[13] = f2.y;
        #pragma unroll
        for (int j = 0; j < KS_; ++j) {
            float wgt = logit[i * KS_ + j];
            #pragma unroll
            for (int d = 0; d < 8; ++d) o8[d] = fmaf(wgt, vr[d + j], o8[d]);
        }
    }

    float* op = out + (((size_t)b * C_ + c) * H_ + ho) * W_ + w0 + half * 8;
    #pragma unroll
    for (int d = 0; d < 8; d += 4) {
        float4 f;
        f.x = fmaxf(o8[d]     * inv, 0.f);
        f.y = fmaxf(o8[d + 1] * inv, 0.f);
        f.z = fmaxf(o8[d + 2] * inv, 0.f);
        f.w = fmaxf(o8[d + 3] * inv, 0.f);
        *reinterpret_cast<float4*>(op + d) = f;
    }
}

extern "C" void kernel_launch(void* const* d_in, const int* in_sizes, int n_in,
                              void* d_out, int out_size, void* d_ws, size_t ws_size,
                              hipStream_t stream) {
    const float* in   = (const float*)d_in[0];
    const float* qw   = (const float*)d_in[1];
    const float* qb   = (const float*)d_in[2];
    const float* kw   = (const float*)d_in[3];
    const float* kb   = (const float*)d_in[4];
    const float* vw   = (const float*)d_in[5];
    const float* vb   = (const float*)d_in[6];
    const float* relh = (const float*)d_in[7];
    const float* relw = (const float*)d_in[8];
    float* out = (float*)d_out;

    float* qkv = (float*)d_ws;   // [B][192][9216]

    dim3 cgrid(NPIX / 32, B_);   // 288 x 4 = 1152 blocks
    mfma_conv_kernel<<<cgrid, 256, 0, stream>>>(in, qw, qb, kw, kb, vw, vb, qkv);

    // MEASUREMENT ROUND: attn launched 5x (idempotent — same qkv -> same out).
    // R7: conv + attn = 44.3 us.  Here: D = conv + 5*attn (+4 graph gaps)
    //   => attn = (D - 44.3)/4,  conv = 44.3 - attn.
    dim3 agrid(B_ * C_ * 3);     // 768 blocks x 384 threads
    attn_kernel<<<agrid, 384, 0, stream>>>(qkv, kb, vb, relh, relw, out);
    attn_kernel<<<agrid, 384, 0, stream>>>(qkv, kb, vb, relh, relw, out);
    attn_kernel<<<agrid, 384, 0, stream>>>(qkv, kb, vb, relh, relw, out);
    attn_kernel<<<agrid, 384, 0, stream>>>(qkv, kb, vb, relh, relw, out);
    attn_kernel<<<agrid, 384, 0, stream>>>(qkv, kb, vb, relh, relw, out);
}

// Round 9
// 42.700 us; speedup vs baseline: 3.6033x; 3.6033x over previous
//
#include <hip/hip_runtime.h>

#define B_ 4
#define C_ 64
#define H_ 96
#define W_ 96
#define KS_ 7
#define NPIX (H_ * W_)   // 9216
#define LDK 108          // K LDS row stride (floats)
#define LDV 112          // V LDS row stride (ushorts) -> 224B rows, 16B-aligned

typedef __attribute__((ext_vector_type(8))) short short8;
typedef __attribute__((ext_vector_type(8))) unsigned short ushort8;
typedef __attribute__((ext_vector_type(4))) float f32x4;

static __device__ inline ushort f2bf(float f) {
    union { float f; unsigned u; } v; v.f = f;
    unsigned r = (v.u + 0x7fff + ((v.u >> 16) & 1)) >> 16;   // RNE
    return (ushort)r;
}
static __device__ inline float bf2f(ushort u) {
    union { unsigned u; float f; } v; v.u = ((unsigned)u) << 16; return v.f;
}

// ws layout: qkv float[B][192][9216] (q rows 0-63, k 64-127, v 128-191), then rel float[64]

// ---- MFMA conv: 32-pix x 192-oc per block; A-frags cvt'd from global in regs ----
__global__ __launch_bounds__(256) void mfma_conv_kernel(
    const float* __restrict__ in,
    const float* __restrict__ qw, const float* __restrict__ qb,
    const float* __restrict__ kw, const float* __restrict__ kb,
    const float* __restrict__ vw, const float* __restrict__ vb,
    const float* __restrict__ relh, const float* __restrict__ relw,
    float* __restrict__ qkv, float* __restrict__ rel_out)
{
    const int b    = blockIdx.y;
    const int pix0 = blockIdx.x * 32;
    const int t    = threadIdx.x;
    const int lane = t & 63;
    const int wv   = t >> 6;

    if (blockIdx.x == 0 && b == 0 && t < 49) {   // rel precompute (one block)
        const int i = t / KS_, j = t % KS_;
        float s = 0.f;
        #pragma unroll
        for (int cc = 0; cc < C_ / 2; ++cc)
            s += relh[cc * KS_ + i] + relw[cc * KS_ + j];
        rel_out[t] = s;
    }

    __shared__ ushort xs[32 * 64];   // [pix][ch] bf16, byte ^= (pix&7)<<4

    {   // stage X tile (32 pix x 64 ch)
        const int pix = t & 31, cg = t >> 5;
        const float* xp = in + (size_t)b * C_ * NPIX + pix0 + pix;
        #pragma unroll
        for (int g = 0; g < 2; ++g) {
            const int ch = (cg + 8 * g) * 4;
            float x0 = xp[(size_t)(ch    ) * NPIX];
            float x1 = xp[(size_t)(ch + 1) * NPIX];
            float x2 = xp[(size_t)(ch + 2) * NPIX];
            float x3 = xp[(size_t)(ch + 3) * NPIX];
            ushort4 u = make_ushort4(f2bf(x0), f2bf(x1), f2bf(x2), f2bf(x3));
            unsigned byte = (unsigned)(pix * 128 + ch * 2) ^ (unsigned)((pix & 7) << 4);
            *reinterpret_cast<ushort4*>(reinterpret_cast<char*>(xs) + byte) = u;
        }
    }

    // A fragments + bias straight from global (overlaps X staging; no barrier dep)
    short8 afr[3][2];
    float  bi[3][4];
    #pragma unroll
    for (int i = 0; i < 3; ++i) {
        const int mt  = 3 * wv + i;                 // wave-uniform
        const int row = mt * 16 + (lane & 15);
        const float* wsrc = (mt < 4) ? qw + row * 64
                          : (mt < 8) ? kw + (row - 64) * 64
                                     : vw + (row - 128) * 64;
        #pragma unroll
        for (int ka = 0; ka < 2; ++ka) {
            const int kk = ka * 32 + (lane >> 4) * 8;
            float4 a = *reinterpret_cast<const float4*>(wsrc + kk);
            float4 c = *reinterpret_cast<const float4*>(wsrc + kk + 4);
            short8 s;
            s[0] = (short)f2bf(a.x); s[1] = (short)f2bf(a.y);
            s[2] = (short)f2bf(a.z); s[3] = (short)f2bf(a.w);
            s[4] = (short)f2bf(c.x); s[5] = (short)f2bf(c.y);
            s[6] = (short)f2bf(c.z); s[7] = (short)f2bf(c.w);
            afr[i][ka] = s;
        }
        const int brow = mt * 16 + (lane >> 4) * 4;
        const float* bsrc = (mt < 4) ? qb + brow
                          : (mt < 8) ? kb + (brow - 64)
                                     : vb + (brow - 128);
        #pragma unroll
        for (int r = 0; r < 4; ++r) bi[i][r] = bsrc[r];
    }
    __syncthreads();

    short8 bfr[2][2];
    #pragma unroll
    for (int nt = 0; nt < 2; ++nt) {
        const int pl = nt * 16 + (lane & 15);
        #pragma unroll
        for (int ka = 0; ka < 2; ++ka) {
            const int kk = ka * 32 + (lane >> 4) * 8;
            unsigned byte = (unsigned)(pl * 128 + kk * 2) ^ (unsigned)((pl & 7) << 4);
            bfr[nt][ka] = *reinterpret_cast<const short8*>(
                reinterpret_cast<const char*>(xs) + byte);
        }
    }
    f32x4 acc[3][2];
    #pragma unroll
    for (int i = 0; i < 3; ++i) {
        f32x4 bv;
        #pragma unroll
        for (int r = 0; r < 4; ++r) bv[r] = bi[i][r];
        #pragma unroll
        for (int nt = 0; nt < 2; ++nt) acc[i][nt] = bv;
    }
    #pragma unroll
    for (int i = 0; i < 3; ++i) {
        #pragma unroll
        for (int nt = 0; nt < 2; ++nt) {
            acc[i][nt] = __builtin_amdgcn_mfma_f32_16x16x32_bf16(
                afr[i][0], bfr[nt][0], acc[i][nt], 0, 0, 0);
            acc[i][nt] = __builtin_amdgcn_mfma_f32_16x16x32_bf16(
                afr[i][1], bfr[nt][1], acc[i][nt], 0, 0, 0);
        }
    }
    #pragma unroll
    for (int i = 0; i < 3; ++i) {
        #pragma unroll
        for (int r = 0; r < 4; ++r) {
            const int row = (3 * wv + i) * 16 + (lane >> 4) * 4 + r;
            float* op = qkv + ((size_t)b * 192 + row) * NPIX + pix0 + (lane & 15);
            #pragma unroll
            for (int nt = 0; nt < 2; ++nt)
                op[nt * 16] = acc[i][nt][r];
        }
    }
}

// ---- attention: K fp32 LDS, V bf16 LDS, rel via scalar loads, exp2 domain ----
__global__ __launch_bounds__(384) void attn_kernel(
    const float* __restrict__ qkv,
    const float* __restrict__ kb, const float* __restrict__ vb,
    const float* __restrict__ rel, float* __restrict__ out)
{
    const int bx   = blockIdx.x;
    const int tile = bx % 3;
    const int c    = (bx / 3) % C_;
    const int b    = bx / (3 * C_);
    const int ho0  = tile * 32;
    const int t    = threadIdx.x;

    __shared__ float  ksl[38 * LDK];    // 16416 B
    __shared__ ushort vsl[38 * LDV];    //  8512 B

    const float kbias = kb[c];
    const float vbias = vb[c];
    const float* kg = qkv + ((size_t)b * 192 +  64 + c) * NPIX;
    const float* vg = qkv + ((size_t)b * 192 + 128 + c) * NPIX;

    // stage: 38 rows x 26 float4-slots = 988 slots each for K and V
    #pragma unroll
    for (int s0 = 0; s0 < 3; ++s0) {
        const int slot = t + s0 * 384;
        if (slot < 38 * 26) {
            const int rl = slot / 26, c4 = (slot - rl * 26) * 4;
            const int gr = ho0 + rl - 3;
            const bool rin = (gr >= 0 && gr < H_);
            const int grc = rin ? gr : 0;
            float kv[4], vv[4];
            #pragma unroll
            for (int e = 0; e < 4; ++e) {
                const int gc  = c4 + e - 3;
                const bool inb = rin && (gc >= 0) && (gc < W_);
                const int gcc = gc < 0 ? 0 : (gc > 95 ? 95 : gc);
                const int gi  = grc * W_ + gcc;
                const float kl = kg[gi], vl = vg[gi];
                kv[e] = inb ? kl : kbias;
                vv[e] = inb ? vl : vbias;
            }
            *reinterpret_cast<float4*>(&ksl[rl * LDK + c4]) =
                make_float4(kv[0], kv[1], kv[2], kv[3]);
            *reinterpret_cast<ushort4*>(&vsl[rl * LDV + c4]) =
                make_ushort4(f2bf(vv[0]), f2bf(vv[1]), f2bf(vv[2]), f2bf(vv[3]));
        }
    }
    __syncthreads();

    const int r0   = t / 12;
    const int rest = t % 12;
    const int w0   = (rest >> 1) * 16;
    const int half = rest & 1;
    const int ho   = ho0 + r0;

    const float LOG2E = 1.44269504f;
    const float* qp = qkv + ((size_t)b * 192 + c) * NPIX + ho * W_ + w0;
    float qs[16];
    #pragma unroll
    for (int tt = 0; tt < 16; tt += 4) {
        float4 f = *reinterpret_cast<const float4*>(qp + tt);
        qs[tt] = f.x * LOG2E; qs[tt + 1] = f.y * LOG2E;
        qs[tt + 2] = f.z * LOG2E; qs[tt + 3] = f.w * LOG2E;
    }
    float qsum = 0.f;
    #pragma unroll
    for (int tt = 0; tt < 16; ++tt) qsum += qs[tt];

    float p[49];
    #pragma unroll
    for (int i = 0; i < KS_; ++i) {
        float kr[22];
        const float* kp = &ksl[(r0 + i) * LDK + w0];
        #pragma unroll
        for (int tt = 0; tt < 20; tt += 4) {
            float4 f = *reinterpret_cast<const float4*>(kp + tt);
            kr[tt] = f.x; kr[tt + 1] = f.y; kr[tt + 2] = f.z; kr[tt + 3] = f.w;
        }
        float2 f2 = *reinterpret_cast<const float2*>(kp + 20);
        kr[20] = f2.x; kr[21] = f2.y;
        #pragma unroll
        for (int j = 0; j < KS_; ++j) {
            float s0 = 0.f, s1 = 0.f, s2 = 0.f, s3 = 0.f;
            #pragma unroll
            for (int tt = 0; tt < 16; tt += 4) {
                s0 = fmaf(qs[tt],     kr[tt + j],     s0);
                s1 = fmaf(qs[tt + 1], kr[tt + 1 + j], s1);
                s2 = fmaf(qs[tt + 2], kr[tt + 2 + j], s2);
                s3 = fmaf(qs[tt + 3], kr[tt + 3 + j], s3);
            }
            // rel[] has uniform address + compile-time index -> scalar loads
            p[i * KS_ + j] = (s0 + s1) + (s2 + s3) + qsum * rel[i * KS_ + j];
        }
    }

    // softmax in log2 domain
    float m0 = p[0], m1 = p[1], m2 = p[2], m3 = p[3];
    #pragma unroll
    for (int kk = 4; kk < 48; kk += 4) {
        m0 = fmaxf(m0, p[kk]);     m1 = fmaxf(m1, p[kk + 1]);
        m2 = fmaxf(m2, p[kk + 2]); m3 = fmaxf(m3, p[kk + 3]);
    }
    float m = fmaxf(fmaxf(fmaxf(m0, m1), fmaxf(m2, m3)), p[48]);

    float e0 = 0.f, e1 = 0.f, e2 = 0.f, e3 = 0.f;
    #pragma unroll
    for (int kk = 0; kk < 48; kk += 4) {
        float a0 = exp2f(p[kk]     - m);
        float a1 = exp2f(p[kk + 1] - m);
        float a2 = exp2f(p[kk + 2] - m);
        float a3 = exp2f(p[kk + 3] - m);
        p[kk] = a0; p[kk + 1] = a1; p[kk + 2] = a2; p[kk + 3] = a3;
        e0 += a0; e1 += a1; e2 += a2; e3 += a3;
    }
    float a48 = exp2f(p[48] - m);
    p[48] = a48;
    const float inv = 1.f / ((e0 + e1) + (e2 + e3) + a48);

    // PV for d = half*8 .. half*8+7 (V from bf16 LDS)
    float o8[8];
    #pragma unroll
    for (int d = 0; d < 8; ++d) o8[d] = 0.f;

    #pragma unroll
    for (int i = 0; i < KS_; ++i) {
        const ushort* vp = &vsl[(r0 + i) * LDV + w0 + half * 8];
        ushort8 u0 = *reinterpret_cast<const ushort8*>(vp);
        ushort8 u1 = *reinterpret_cast<const ushort8*>(vp + 8);
        float vf[14];
        #pragma unroll
        for (int e = 0; e < 8; ++e) vf[e] = bf2f(u0[e]);
        #pragma unroll
        for (int e = 0; e < 6; ++e) vf[8 + e] = bf2f(u1[e]);
        #pragma unroll
        for (int j = 0; j < KS_; ++j) {
            float wgt = p[i * KS_ + j];
            #pragma unroll
            for (int d = 0; d < 8; ++d) o8[d] = fmaf(wgt, vf[d + j], o8[d]);
        }
    }

    float* op = out + (((size_t)b * C_ + c) * H_ + ho) * W_ + w0 + half * 8;
    #pragma unroll
    for (int d = 0; d < 8; d += 4) {
        float4 f;
        f.x = fmaxf(o8[d]     * inv, 0.f);
        f.y = fmaxf(o8[d + 1] * inv, 0.f);
        f.z = fmaxf(o8[d + 2] * inv, 0.f);
        f.w = fmaxf(o8[d + 3] * inv, 0.f);
        *reinterpret_cast<float4*>(op + d) = f;
    }
}

extern "C" void kernel_launch(void* const* d_in, const int* in_sizes, int n_in,
                              void* d_out, int out_size, void* d_ws, size_t ws_size,
                              hipStream_t stream) {
    const float* in   = (const float*)d_in[0];
    const float* qw   = (const float*)d_in[1];
    const float* qb   = (const float*)d_in[2];
    const float* kw   = (const float*)d_in[3];
    const float* kb   = (const float*)d_in[4];
    const float* vw   = (const float*)d_in[5];
    const float* vb   = (const float*)d_in[6];
    const float* relh = (const float*)d_in[7];
    const float* relw = (const float*)d_in[8];
    float* out = (float*)d_out;

    float* qkv = (float*)d_ws;                       // [B][192][9216]
    float* rel = qkv + (size_t)B_ * 192 * NPIX;      // [64]

    dim3 cgrid(NPIX / 32, B_);   // 288 x 4 = 1152 blocks
    mfma_conv_kernel<<<cgrid, 256, 0, stream>>>(in, qw, qb, kw, kb, vw, vb,
                                                relh, relw, qkv, rel);

    dim3 agrid(B_ * C_ * 3);     // 768 blocks x 384 threads
    attn_kernel<<<agrid, 384, 0, stream>>>(qkv, kb, vb, rel, out);
}